// Round 1
// baseline (138.638 us; speedup 1.0000x reference)
//
#include <hip/hip_runtime.h>

// Problem constants (from reference setup_inputs):
// heat_preds / heatmaps: [S=5, B=16, C=11, H=128, W=128] f32
// label_preds: [S, B, NCLASS=11, F=7] f32 ; labels: [B, 11, 7] f32
// Outputs (concatenated): combined_loss [B,S] then labels_loss [B,S] -> 160 f32
#define SS 5
#define BB 16
#define CC 11
#define HW 16384  // 128*128
#define CF 77     // 11*7

// Kernel 1: zero the combined_loss region (atomics target) + compute labels_loss.
__global__ void init_and_labels_kernel(const float* __restrict__ label_preds,
                                       const float* __restrict__ labels,
                                       float* __restrict__ out) {
    int t = threadIdx.x;
    if (t < SS * BB) {
        int s = t / BB;
        int b = t % BB;
        out[b * SS + s] = 0.0f;  // combined_loss accumulator
        const float* lp = label_preds + (size_t)(s * BB + b) * CF;
        const float* lb = labels + (size_t)b * CF;
        float sum = 0.0f;
#pragma unroll
        for (int i = 0; i < CF; ++i) {
            float d = lp[i] - lb[i];
            sum += d * d;
        }
        out[SS * BB + b * SS + s] = sum;
    }
}

// Kernel 2: one block per (s,b,c) slice of 16384 contiguous floats.
// Block-reduce sum of squared diffs, then one atomicAdd into out[b*S+s].
__global__ __launch_bounds__(256) void heat_loss_kernel(const float* __restrict__ hp,
                                                        const float* __restrict__ hm,
                                                        float* __restrict__ out) {
    const int blk = blockIdx.x;           // s*(B*C) + b*C + c
    const int b = (blk / CC) % BB;
    const int s = blk / (BB * CC);
    const size_t base = (size_t)blk * HW;

    const float4* __restrict__ p = (const float4*)(hp + base);
    const float4* __restrict__ q = (const float4*)(hm + base);

    const int t = threadIdx.x;
    float sum = 0.0f;
#pragma unroll
    for (int i = 0; i < HW / 4 / 256; ++i) {  // 16 iterations
        float4 a = p[t + i * 256];
        float4 m = q[t + i * 256];
        float d0 = a.x - m.x;
        float d1 = a.y - m.y;
        float d2 = a.z - m.z;
        float d3 = a.w - m.w;
        sum += d0 * d0 + d1 * d1 + d2 * d2 + d3 * d3;
    }

    // wave-64 shuffle reduction
#pragma unroll
    for (int off = 32; off > 0; off >>= 1) sum += __shfl_down(sum, off, 64);

    __shared__ float ws[4];
    const int lane = t & 63;
    const int wave = t >> 6;
    if (lane == 0) ws[wave] = sum;
    __syncthreads();
    if (t == 0) {
        float tot = ws[0] + ws[1] + ws[2] + ws[3];
        atomicAdd(&out[b * SS + s], tot * (1.0f / (float)HW));
    }
}

extern "C" void kernel_launch(void* const* d_in, const int* in_sizes, int n_in,
                              void* d_out, int out_size, void* d_ws, size_t ws_size,
                              hipStream_t stream) {
    const float* heat_preds = (const float*)d_in[0];
    const float* heatmaps = (const float*)d_in[1];
    const float* label_preds = (const float*)d_in[2];
    const float* labels = (const float*)d_in[3];
    float* out = (float*)d_out;

    // Zero combined region + labels loss (must precede atomic kernel; stream-ordered).
    init_and_labels_kernel<<<1, 128, 0, stream>>>(label_preds, labels, out);

    // One block per (s,b,c) slice: 5*16*11 = 880 blocks.
    heat_loss_kernel<<<SS * BB * CC, 256, 0, stream>>>(heat_preds, heatmaps, out);
}

// Round 2
// 131.942 us; speedup vs baseline: 1.0507x; 1.0507x over previous
//
#include <hip/hip_runtime.h>

// Problem constants (from reference setup_inputs):
// heat_preds / heatmaps: [S=5, B=16, C=11, H=128, W=128] f32
// label_preds: [S, B, NCLASS=11, F=7] f32 ; labels: [B, 11, 7] f32
// Outputs (concatenated flat): combined_loss [B,S] then labels_loss [B,S] -> 160 f32
#define SS 5
#define BB 16
#define CC 11
#define HW 16384       // 128*128
#define CF 77          // 11*7
#define CHUNK 4096     // floats per partial block
#define NCHUNK 4       // chunks per (s,b,c) slice = HW/CHUNK
#define NPART (SS * BB * CC * NCHUNK)   // 3520 partial blocks
#define PPO (CC * NCHUNK)               // partials per output (s,b) = 44

// Kernel A: one block per 4096-float chunk. Sum of squared diffs -> ws[blk].
// 3520 blocks x 256 threads: ~13.75 blocks/CU, saturates the 32-wave/CU cap
// (the 880-block version stalled at 22.8% occupancy, latency-bound).
__global__ __launch_bounds__(256) void heat_partial_kernel(const float* __restrict__ hp,
                                                           const float* __restrict__ hm,
                                                           float* __restrict__ partials) {
    const int blk = blockIdx.x;
    const size_t base = (size_t)blk * CHUNK;
    const float4* __restrict__ p = (const float4*)(hp + base);
    const float4* __restrict__ q = (const float4*)(hm + base);

    const int t = threadIdx.x;
    float sum = 0.0f;
#pragma unroll
    for (int i = 0; i < CHUNK / 4 / 256; ++i) {  // 4 iterations, 8 loads in flight
        float4 a = p[t + i * 256];
        float4 m = q[t + i * 256];
        float d0 = a.x - m.x;
        float d1 = a.y - m.y;
        float d2 = a.z - m.z;
        float d3 = a.w - m.w;
        sum += d0 * d0 + d1 * d1 + d2 * d2 + d3 * d3;
    }

#pragma unroll
    for (int off = 32; off > 0; off >>= 1) sum += __shfl_down(sum, off, 64);

    __shared__ float wsum[4];
    const int lane = t & 63;
    const int wave = t >> 6;
    if (lane == 0) wsum[wave] = sum;
    __syncthreads();
    if (t == 0) partials[blk] = wsum[0] + wsum[1] + wsum[2] + wsum[3];
}

// Kernel B: one 64-lane block per output (s,b). Reduces the 44 contiguous
// partials (chunk index layout: ((s*B+b)*C+c)*4+k -> [sb*44 .. sb*44+44)) and
// fuses the labels loss. No atomics, no zero-init needed anywhere.
__global__ __launch_bounds__(64) void final_kernel(const float* __restrict__ partials,
                                                   const float* __restrict__ label_preds,
                                                   const float* __restrict__ labels,
                                                   float* __restrict__ out) {
    const int sb = blockIdx.x;   // s*BB + b
    const int s = sb / BB;
    const int b = sb % BB;
    const int lane = threadIdx.x;

    float h = (lane < PPO) ? partials[sb * PPO + lane] : 0.0f;

    const float* lp = label_preds + (size_t)sb * CF;
    const float* lb = labels + (size_t)b * CF;
    float l = 0.0f;
    if (lane < CF) {  // always true for 64 lanes, kept for clarity
        float d = lp[lane] - lb[lane];
        l = d * d;
    }
    const int i2 = lane + 64;
    if (i2 < CF) {  // lanes 0..12 take the tail elements 64..76
        float d = lp[i2] - lb[i2];
        l += d * d;
    }

#pragma unroll
    for (int off = 32; off > 0; off >>= 1) {
        h += __shfl_down(h, off, 64);
        l += __shfl_down(l, off, 64);
    }

    if (lane == 0) {
        out[b * SS + s] = h * (1.0f / (float)HW);   // combined_loss [B,S]
        out[SS * BB + b * SS + s] = l;              // labels_loss   [B,S]
    }
}

extern "C" void kernel_launch(void* const* d_in, const int* in_sizes, int n_in,
                              void* d_out, int out_size, void* d_ws, size_t ws_size,
                              hipStream_t stream) {
    const float* heat_preds = (const float*)d_in[0];
    const float* heatmaps = (const float*)d_in[1];
    const float* label_preds = (const float*)d_in[2];
    const float* labels = (const float*)d_in[3];
    float* out = (float*)d_out;
    float* partials = (float*)d_ws;  // 3520 floats = 14 KB

    heat_partial_kernel<<<NPART, 256, 0, stream>>>(heat_preds, heatmaps, partials);
    final_kernel<<<SS * BB, 64, 0, stream>>>(partials, label_preds, labels, out);
}